// Round 3
// baseline (186.012 us; speedup 1.0000x reference)
//
#include <hip/hip_runtime.h>
#include <math.h>

// Problem constants (from reference): B=8, Cin=32, Cout=32, S=256,
// REGION=64, OVERLAP=0 -> 4x4 regions, MAX_M=16.
#define NB 8
#define CIN 32
#define COUT 32
#define SS 256
#define REG 64
#define NMAX 16

// Workspace layout (bytes):
#define AVG_OFF   0
#define C64_OFF   4096
#define CN_OFF    4352
#define Y_OFF     8192            // 1024 io * 1496 * 4B ~ 6.13 MB
#define YF_OFF    (8u << 20)      // pre-flipped copy of Y, same layout
#define XE_OFF    (16u << 20)     // 4 MB
#define XO_OFF    (20u << 20)     // 4 MB

// Per-block recomputation of the region's mode count n.
// MUST be bit-identical everywhere so every consumer agrees.
__device__ __forceinline__ int region_n(const float* __restrict__ avg, int r, int b) {
    float mn = avg[r * 8], mx = mn;
    for (int bb = 1; bb < NB; ++bb) {
        float v = avg[r * 8 + bb];
        mn = fminf(mn, v);
        mx = fmaxf(mx, v);
    }
    float d = mx - mn;
    bool ok = ((double)d > 1e-8);
    float norm = ok ? (avg[r * 8 + b] - mn) / d : 0.0f;
    float tt = norm * 15.0f;
    int nv = (int)tt + 1;
    return nv > NMAX ? NMAX : nv;
}

// One launch, three block roles:
//   bx <  128 : region means (r = bx&15, b = bx>>4)
//   bx == 128 : global cas tables (for k_fwd / k_zout)
//   bx >  128 : weight DHTs, io = bx-129; builds its own local cas table.
// Writes Y and the pre-flipped Yf.  (unchanged — verified)
__global__ void k_prep(const float* __restrict__ err, const float* __restrict__ wts,
                       float* __restrict__ avg, float* __restrict__ cyc64,
                       float* __restrict__ cycN, float* __restrict__ Y,
                       float* __restrict__ Yf) {
    int bx = blockIdx.x;
    int t = threadIdx.x;

    if (bx < 128) {
        int r = bx & 15, b = bx >> 4;
        int ri = r >> 2, rj = r & 3;
        const float* base = err + ((size_t)b * SS + ri * REG) * SS + rj * REG;
        double s = 0.0;
        for (int it = 0; it < 16; ++it) {
            int u = it * 4 + (t >> 6);
            int v = t & 63;
            s += (double)base[(size_t)u * SS + v];
        }
        __shared__ double sm[256];
        sm[t] = s;
        __syncthreads();
        for (int w = 128; w > 0; w >>= 1) {
            if (t < w) sm[t] += sm[t + w];
            __syncthreads();
        }
        if (t == 0) avg[r * 8 + b] = (float)(sm[0] / 4096.0);
        return;
    }

    if (bx == 128) {
        if (t < 64) {
            double a = (2.0 * M_PI / 64.0) * (double)t;
            cyc64[t] = (float)(cos(a) + sin(a));
        } else if (t < 64 + 136) {
            int e = t - 64;
            int n = 1;
            while (n * (n + 1) / 2 <= e) ++n;
            int j = e - n * (n - 1) / 2;
            double a = (2.0 * M_PI / (double)n) * (double)j;
            cycN[e] = (float)(cos(a) + sin(a));
        }
        return;
    }

    // ---- weight block ----
    int io = bx - 129;
    __shared__ float Wt[256];
    __shared__ float T1[256];
    __shared__ float T2[256];
    __shared__ float cnAll[136];
    if (t < 136) {
        int e = t;
        int n = 1;
        while (n * (n + 1) / 2 <= e) ++n;
        int j = e - n * (n - 1) / 2;
        double a = (2.0 * M_PI / (double)n) * (double)j;
        cnAll[e] = (float)(cos(a) + sin(a));
    }
    Wt[t] = wts[(size_t)io * 256 + t];
    __syncthreads();

    for (int n = 1; n <= NMAX; ++n) {
        int nn = n * n;
        const float* cnL = &cnAll[(n * (n - 1)) / 2];
        int p = 0, q = 0;
        if (t < nn) { p = t / n; q = t - p * n; }
        if (t < nn) {
            float acc = 0.f;
            int idx = 0;
            for (int v = 0; v < n; ++v) {
                acc += Wt[p * 16 + v] * cnL[idx];
                idx += q; if (idx >= n) idx -= n;
            }
            T1[p * n + q] = acc;
        }
        __syncthreads();
        if (t < nn) {
            float acc = 0.f;
            int idx = 0;
            for (int u = 0; u < n; ++u) {
                acc += T1[u * n + q] * cnL[idx];
                idx += p; if (idx >= n) idx -= n;
            }
            T2[t] = acc;
        }
        __syncthreads();
        if (t < nn) {
            int pf = (p == 0) ? 0 : n - p;
            int qf = (q == 0) ? 0 : n - q;
            float v = 0.5f * (T2[p * n + q] + T2[pf * n + q] + T2[p * n + qf] - T2[pf * n + qf]);
            int m = n - 1;
            int ps2 = m * (m + 1) * (2 * m + 1) / 6;
            size_t basei = (size_t)1024 * ps2 + (size_t)io * nn;
            Y[basei + t] = v;
            int fk = (t == 0) ? 0 : nn - t;
            Yf[basei + fk] = v;
        }
        __syncthreads();  // T2 reads done before next iter's stage-2 rewrite
    }
}

// One block per (i, r, b).  (unchanged — verified)
__global__ void k_fwd(const float* __restrict__ x, const float* __restrict__ avg,
                      const float* __restrict__ cyc64, const float* __restrict__ cycN,
                      float* __restrict__ Xe, float* __restrict__ Xo) {
    int i = blockIdx.x, r = blockIdx.y, b = blockIdx.z;
    int n = region_n(avg, r, b);
    int nn = n * n;
    int ri = r >> 2, rj = r & 3;
    int t = threadIdx.x;

    __shared__ __align__(16) float R[64 * 64];      // reused as partial buffer P
    __shared__ __align__(16) float M1[16 * 68];
    __shared__ float H[256];
    __shared__ float T1[256];
    __shared__ float T2[256];
    __shared__ float cyc64L[64];
    __shared__ float cnL[16];

    if (t < 64) cyc64L[t] = cyc64[t];
    if (t < n)  cnL[t] = cycN[(n * (n - 1)) / 2 + t];

    const float* base = x + (((size_t)(b * CIN + i)) * SS + ri * REG) * SS + rj * REG;
    float4* R4 = (float4*)R;
    {
        int u0 = t >> 4, c4 = t & 15;
        for (int it = 0; it < 4; ++it) {
            int u = it * 16 + u0;
            R4[u * 16 + c4] = *(const float4*)(base + (size_t)u * SS + c4 * 4);
        }
    }
    __syncthreads();

    // stage 1: M1[p][v] = sum_u cas64(p*u) * R[u][v], p < n.
    {
        int uq = t >> 6, ps = (t >> 4) & 3, vg = t & 15;
        int p0 = ps, p1 = ps + 4, p2 = ps + 8, p3 = ps + 12;
        int i0 = (p0 * (uq << 4)) & 63;
        int i1 = (p1 * (uq << 4)) & 63;
        int i2 = (p2 * (uq << 4)) & 63;
        int i3 = (p3 * (uq << 4)) & 63;
        float4 a0 = {0.f,0.f,0.f,0.f}, a1 = a0, a2 = a0, a3 = a0;
        int ubase = (uq << 4) * 16 + vg;
        for (int uu = 0; uu < 16; ++uu) {
            float4 rv = R4[ubase + uu * 16];
            if (p0 < n) { float c = cyc64L[i0];
                a0.x += c*rv.x; a0.y += c*rv.y; a0.z += c*rv.z; a0.w += c*rv.w; }
            if (p1 < n) { float c = cyc64L[i1];
                a1.x += c*rv.x; a1.y += c*rv.y; a1.z += c*rv.z; a1.w += c*rv.w; }
            if (p2 < n) { float c = cyc64L[i2];
                a2.x += c*rv.x; a2.y += c*rv.y; a2.z += c*rv.z; a2.w += c*rv.w; }
            if (p3 < n) { float c = cyc64L[i3];
                a3.x += c*rv.x; a3.y += c*rv.y; a3.z += c*rv.z; a3.w += c*rv.w; }
            i0 = (i0 + p0) & 63; i1 = (i1 + p1) & 63;
            i2 = (i2 + p2) & 63; i3 = (i3 + p3) & 63;
        }
        __syncthreads();            // all R reads complete before reuse as P
        float4* P4 = R4;            // P[uq][p][vg]
        int pb = (uq << 8) + vg;
        if (p0 < n) P4[pb + p0 * 16] = a0;
        if (p1 < n) P4[pb + p1 * 16] = a1;
        if (p2 < n) P4[pb + p2 * 16] = a2;
        if (p3 < n) P4[pb + p3 * 16] = a3;
        __syncthreads();
        int pr = t >> 4, vr = t & 15;
        if (pr < n) {
            float4 q0 = P4[pr * 16 + vr];
            float4 q1 = P4[256 + pr * 16 + vr];
            float4 q2 = P4[512 + pr * 16 + vr];
            float4 q3 = P4[768 + pr * 16 + vr];
            float4 s;
            s.x = (q0.x + q1.x) + (q2.x + q3.x);
            s.y = (q0.y + q1.y) + (q2.y + q3.y);
            s.z = (q0.z + q1.z) + (q2.z + q3.z);
            s.w = (q0.w + q1.w) + (q2.w + q3.w);
            *(float4*)&M1[pr * 68 + vr * 4] = s;
        }
    }
    __syncthreads();

    int p = 0, q = 0;
    if (t < nn) { p = t / n; q = t - p * n; }

    // stage 2: H[p][q] = sum_v M1[p][v] * cas64(q*v)
    if (t < nn) {
        float acc = 0.f;
        int idx = 0;
        for (int v = 0; v < 64; ++v) {
            acc += M1[p * 68 + v] * cyc64L[idx];
            idx = (idx + q) & 63;
        }
        H[t] = acc;
    }
    __syncthreads();

    // stage 3: true 2-D DHT of H (n x n) = row-column + correction
    if (t < nn) {
        float acc = 0.f;
        int idx = 0;
        for (int v = 0; v < n; ++v) {
            acc += H[p * n + v] * cnL[idx];
            idx += q; if (idx >= n) idx -= n;
        }
        T1[p * n + q] = acc;
    }
    __syncthreads();
    if (t < nn) {
        float acc = 0.f;
        int idx = 0;
        for (int u = 0; u < n; ++u) {
            acc += T1[u * n + q] * cnL[idx];
            idx += p; if (idx >= n) idx -= n;
        }
        T2[t] = acc;
    }
    __syncthreads();
    if (t < nn) {
        int pf = (p == 0) ? 0 : n - p;
        int qf = (q == 0) ? 0 : n - q;
        H[t] = 0.5f * (T2[p * n + q] + T2[pf * n + q] + T2[p * n + qf] - T2[pf * n + qf]);
    }
    __syncthreads();

    if (t < nn) {
        int fk = (t == 0) ? 0 : nn - t;
        float a = H[t], c = H[fk];
        size_t o = (((size_t)(b * 16 + r)) * CIN + i) * 256 + t;
        Xe[o] = 0.5f * (a + c);
        Xo[o] = 0.5f * (a - c);
    }
}

// Fused channel-mix + inverse, ONE output per block: grid (o=32, br=128).
// The i-sum is split across the 4 waves (ig = t>>6 owns i in [ig*8, ig*8+8));
// each thread covers k-slots {k0, k0+64, k0+128, k0+192} < nn. All 256
// threads are active for every n, and the critical n=16 blocks issue 128
// loads/thread (16 independent per i-iter) instead of 320. 4-way LDS
// reduction, then the inverse dht2 + n->64 expansion runs ONCE per block.
__global__ void k_zout(const float* __restrict__ Xe, const float* __restrict__ Xo,
                       const float* __restrict__ Y, const float* __restrict__ Yf,
                       const float* __restrict__ avg, const float* __restrict__ cyc64,
                       const float* __restrict__ cycN, float* __restrict__ out) {
    int o  = blockIdx.x;
    int br = blockIdx.y;
    int b = br >> 4, r = br & 15;
    int n = region_n(avg, r, b);
    int nn = n * n;
    int t = threadIdx.x;

    __shared__ float zpart[4][256];
    __shared__ float Zs[256];
    __shared__ float T1[256];
    __shared__ float T2[256];
    __shared__ float Bk[256];
    __shared__ __align__(16) float E1[16 * 64];
    __shared__ __align__(16) float CTo[16 * 16 * 4];   // [p][u0] -> cas(p*(u0+16k))
    __shared__ float cyc64L[64];
    __shared__ float cnL[16];

    if (t < 64) cyc64L[t] = cyc64[t];
    if (t < n)  cnL[t] = cycN[(n * (n - 1)) / 2 + t];

    // ---- z-phase (partial over i): issue the global loads first.
    int ig = t >> 6, k0 = t & 63;
    {
        int m = n - 1;
        int ps2 = m * (m + 1) * (2 * m + 1) / 6;
        const float* Yb  = Y  + (size_t)1024 * ps2;
        const float* Yfb = Yf + (size_t)1024 * ps2;
        size_t xb = (size_t)br * CIN * 256;
        float a0 = 0.f, a1 = 0.f, a2 = 0.f, a3 = 0.f;
        int k1 = k0 + 64, k2 = k0 + 128, k3 = k0 + 192;
#pragma unroll 2
        for (int ii = 0; ii < 8; ++ii) {
            int i = ig * 8 + ii;
            const float* xep = Xe + xb + (size_t)i * 256;
            const float* xop = Xo + xb + (size_t)i * 256;
            const float* yp  = Yb  + (size_t)(i * COUT + o) * nn;
            const float* yfp = Yfb + (size_t)(i * COUT + o) * nn;
            if (k0 < nn) a0 += xep[k0] * yp[k0] + xop[k0] * yfp[k0];
            if (k1 < nn) a1 += xep[k1] * yp[k1] + xop[k1] * yfp[k1];
            if (k2 < nn) a2 += xep[k2] * yp[k2] + xop[k2] * yfp[k2];
            if (k3 < nn) a3 += xep[k3] * yp[k3] + xop[k3] * yfp[k3];
        }
        zpart[ig][k0]  = a0;
        zpart[ig][k1]  = a1;
        zpart[ig][k2]  = a2;
        zpart[ig][k3]  = a3;
    }
    __syncthreads();   // zpart + cyc64L/cnL visible

    // coefficient table for the final expansion (overlaps with reduce)
    {
        int pp = t >> 4, u0 = t & 15;
        float4 c;
        c.x = cyc64L[(pp * u0) & 63];
        c.y = cyc64L[(pp * (u0 + 16)) & 63];
        c.z = cyc64L[(pp * (u0 + 32)) & 63];
        c.w = cyc64L[(pp * (u0 + 48)) & 63];
        *(float4*)&CTo[t * 4] = c;
    }
    if (t < nn)
        Zs[t] = (zpart[0][t] + zpart[1][t]) + (zpart[2][t] + zpart[3][t]);

    int p = 0, q = 0;
    if (t < nn) { p = t / n; q = t - p * n; }
    __syncthreads();

    // inverse dht2 (row-column + correction), / nn
    if (t < nn) {
        float acc = 0.f;
        int idx = 0;
        for (int v = 0; v < n; ++v) {
            acc += Zs[p * n + v] * cnL[idx];
            idx += q; if (idx >= n) idx -= n;
        }
        T1[p * n + q] = acc;
    }
    __syncthreads();
    if (t < nn) {
        float acc = 0.f;
        int idx = 0;
        for (int u = 0; u < n; ++u) {
            acc += T1[u * n + q] * cnL[idx];
            idx += p; if (idx >= n) idx -= n;
        }
        T2[t] = acc;
    }
    __syncthreads();
    if (t < nn) {
        int pf = (p == 0) ? 0 : n - p;
        int qf = (q == 0) ? 0 : n - q;
        Bk[t] = 0.5f * (T2[p * n + q] + T2[pf * n + q] + T2[p * n + qf] - T2[pf * n + qf])
                / (float)nn;
    }
    __syncthreads();

    // E1[p][v] = sum_q Bk[p*n+q] * cas64(q*v)
    for (int mm = t; mm < n * 64; mm += 256) {
        int pp = mm >> 6, v = mm & 63;
        float acc = 0.f;
        int idx = 0;
        for (int qq = 0; qq < n; ++qq) {
            acc += Bk[pp * n + qq] * cyc64L[idx];
            idx = (idx + v) & 63;
        }
        E1[pp * 64 + v] = acc;
    }
    __syncthreads();

    // out[u][v] = (1/4096) sum_p E1[p][v] * cas64(p*u); p-outer, 4 u-rows/thread.
    int ri = r >> 2, rj = r & 3;
    float* ob = out + (((size_t)(b * COUT + o)) * SS + ri * REG) * SS + rj * REG;
    const float4* E14 = (const float4*)E1;
    const float4* CT4 = (const float4*)CTo;
    const float inv = 1.0f / 4096.0f;
    int u0 = t >> 4, vg = t & 15;
    float4 aA = {0.f,0.f,0.f,0.f}, aB = aA, aC = aA, aD = aA;
    for (int pp = 0; pp < n; ++pp) {
        float4 e = E14[pp * 16 + vg];
        float4 c = CT4[pp * 16 + u0];
        aA.x += c.x*e.x; aA.y += c.x*e.y; aA.z += c.x*e.z; aA.w += c.x*e.w;
        aB.x += c.y*e.x; aB.y += c.y*e.y; aB.z += c.y*e.z; aB.w += c.y*e.w;
        aC.x += c.z*e.x; aC.y += c.z*e.y; aC.z += c.z*e.z; aC.w += c.z*e.w;
        aD.x += c.w*e.x; aD.y += c.w*e.y; aD.z += c.w*e.z; aD.w += c.w*e.w;
    }
    aA.x *= inv; aA.y *= inv; aA.z *= inv; aA.w *= inv;
    aB.x *= inv; aB.y *= inv; aB.z *= inv; aB.w *= inv;
    aC.x *= inv; aC.y *= inv; aC.z *= inv; aC.w *= inv;
    aD.x *= inv; aD.y *= inv; aD.z *= inv; aD.w *= inv;
    *(float4*)(ob + (size_t)(u0)      * SS + vg * 4) = aA;
    *(float4*)(ob + (size_t)(16 + u0) * SS + vg * 4) = aB;
    *(float4*)(ob + (size_t)(32 + u0) * SS + vg * 4) = aC;
    *(float4*)(ob + (size_t)(48 + u0) * SS + vg * 4) = aD;
}

extern "C" void kernel_launch(void* const* d_in, const int* in_sizes, int n_in,
                              void* d_out, int out_size, void* d_ws, size_t ws_size,
                              hipStream_t stream) {
    const float* x   = (const float*)d_in[0];
    const float* err = (const float*)d_in[1];
    const float* wts = (const float*)d_in[2];
    float* out = (float*)d_out;
    char* ws = (char*)d_ws;

    float* avg   = (float*)(ws + AVG_OFF);
    float* cyc64 = (float*)(ws + C64_OFF);
    float* cycN  = (float*)(ws + CN_OFF);
    float* Y     = (float*)(ws + Y_OFF);
    float* Yf    = (float*)(ws + YF_OFF);
    float* Xe    = (float*)(ws + XE_OFF);
    float* Xo    = (float*)(ws + XO_OFF);

    k_prep<<<dim3(128 + 1 + CIN * COUT), 256, 0, stream>>>(err, wts, avg, cyc64, cycN, Y, Yf);
    k_fwd<<<dim3(CIN, 16, NB), 256, 0, stream>>>(x, avg, cyc64, cycN, Xe, Xo);
    k_zout<<<dim3(COUT, 128), 256, 0, stream>>>(Xe, Xo, Y, Yf, avg, cyc64, cycN, out);
}

// Round 4
// 179.167 us; speedup vs baseline: 1.0382x; 1.0382x over previous
//
#include <hip/hip_runtime.h>
#include <math.h>

// Problem constants (from reference): B=8, Cin=32, Cout=32, S=256,
// REGION=64, OVERLAP=0 -> 4x4 regions, MAX_M=16.
#define NB 8
#define CIN 32
#define COUT 32
#define SS 256
#define REG 64
#define NMAX 16

// Workspace layout (bytes):
#define AVG_OFF   0
#define C64_OFF   4096
#define CN_OFF    4352
#define Y_OFF     8192            // 1024 io * 1520 (padded) * 4B ~ 6.23 MB
#define YF_OFF    (8u << 20)      // pre-flipped copy of Y, same padded layout
#define XE_OFF    (16u << 20)     // 4 MB
#define XO_OFF    (20u << 20)     // 4 MB

// Cumulative padded offsets: CPS[n] = sum_{m<n} roundup4(m*m). Per-io stride
// for mode n is roundup4(n*n); pad entries are ZERO so float4 z-phase loads
// over the pad contribute nothing.
__device__ __constant__ int CPS16[17] =
    {0, 0, 4, 8, 20, 36, 64, 100, 152, 216, 300, 400, 524, 668, 840, 1036, 1264};

// Per-block recomputation of the region's mode count n.
// MUST be bit-identical everywhere so every consumer agrees.
__device__ __forceinline__ int region_n(const float* __restrict__ avg, int r, int b) {
    float mn = avg[r * 8], mx = mn;
    for (int bb = 1; bb < NB; ++bb) {
        float v = avg[r * 8 + bb];
        mn = fminf(mn, v);
        mx = fmaxf(mx, v);
    }
    float d = mx - mn;
    bool ok = ((double)d > 1e-8);
    float norm = ok ? (avg[r * 8 + b] - mn) / d : 0.0f;
    float tt = norm * 15.0f;
    int nv = (int)tt + 1;
    return nv > NMAX ? NMAX : nv;
}

// One launch, three block roles:
//   bx <  128 : region means (r = bx&15, b = bx>>4), float4 loads
//   bx == 128 : global cas tables (for k_fwd / k_zout)
//   bx >  128 : weight DHTs, io = bx-129; padded Y/Yf layout + zeroed pad.
__global__ void k_prep(const float* __restrict__ err, const float* __restrict__ wts,
                       float* __restrict__ avg, float* __restrict__ cyc64,
                       float* __restrict__ cycN, float* __restrict__ Y,
                       float* __restrict__ Yf) {
    int bx = blockIdx.x;
    int t = threadIdx.x;

    if (bx < 128) {
        int r = bx & 15, b = bx >> 4;
        int ri = r >> 2, rj = r & 3;
        const float* base = err + ((size_t)b * SS + ri * REG) * SS + rj * REG;
        double s = 0.0;
        for (int it = 0; it < 4; ++it) {
            int f = it * 256 + t;          // float4 index within the 64x64 region
            int u = f >> 4, c4 = f & 15;
            float4 v = *(const float4*)(base + (size_t)u * SS + c4 * 4);
            s += (double)v.x + (double)v.y + (double)v.z + (double)v.w;
        }
        __shared__ double sm[256];
        sm[t] = s;
        __syncthreads();
        for (int w = 128; w > 0; w >>= 1) {
            if (t < w) sm[t] += sm[t + w];
            __syncthreads();
        }
        if (t == 0) avg[r * 8 + b] = (float)(sm[0] / 4096.0);
        return;
    }

    if (bx == 128) {
        if (t < 64) {
            double a = (2.0 * M_PI / 64.0) * (double)t;
            cyc64[t] = (float)(cos(a) + sin(a));
        } else if (t < 64 + 136) {
            int e = t - 64;
            int n = 1;
            while (n * (n + 1) / 2 <= e) ++n;
            int j = e - n * (n - 1) / 2;
            double a = (2.0 * M_PI / (double)n) * (double)j;
            cycN[e] = (float)(cos(a) + sin(a));
        }
        return;
    }

    // ---- weight block ----
    int io = bx - 129;
    __shared__ float Wt[256];
    __shared__ float T1[256];
    __shared__ float T2[256];
    __shared__ float cnAll[136];
    if (t < 136) {
        int e = t;
        int n = 1;
        while (n * (n + 1) / 2 <= e) ++n;
        int j = e - n * (n - 1) / 2;
        double a = (2.0 * M_PI / (double)n) * (double)j;
        cnAll[e] = (float)(cos(a) + sin(a));
    }
    Wt[t] = wts[(size_t)io * 256 + t];
    __syncthreads();

    for (int n = 1; n <= NMAX; ++n) {
        int nn = n * n;
        int nnp = (nn + 3) & ~3;
        const float* cnL = &cnAll[(n * (n - 1)) / 2];
        int p = 0, q = 0;
        if (t < nn) { p = t / n; q = t - p * n; }
        if (t < nn) {
            float acc = 0.f;
            int idx = 0;
            for (int v = 0; v < n; ++v) {
                acc += Wt[p * 16 + v] * cnL[idx];
                idx += q; if (idx >= n) idx -= n;
            }
            T1[p * n + q] = acc;
        }
        __syncthreads();
        if (t < nn) {
            float acc = 0.f;
            int idx = 0;
            for (int u = 0; u < n; ++u) {
                acc += T1[u * n + q] * cnL[idx];
                idx += p; if (idx >= n) idx -= n;
            }
            T2[t] = acc;
        }
        __syncthreads();
        size_t basei = (size_t)1024 * CPS16[n] + (size_t)io * nnp;
        if (t < nn) {
            int pf = (p == 0) ? 0 : n - p;
            int qf = (q == 0) ? 0 : n - q;
            float v = 0.5f * (T2[p * n + q] + T2[pf * n + q] + T2[p * n + qf] - T2[pf * n + qf]);
            Y[basei + t] = v;
            int fk = (t == 0) ? 0 : nn - t;
            Yf[basei + fk] = v;
        } else if (t < nnp) {
            Y[basei + t]  = 0.f;   // zero pad -> float4 loads over pad are inert
            Yf[basei + t] = 0.f;
        }
        __syncthreads();  // T2 reads done before next iter's stage-2 rewrite
    }
}

// One block per (i, r, b). Zero-fills the Xe/Xo tail (t >= nn) so the padded
// float4 z-phase never multiplies poison.
__global__ void k_fwd(const float* __restrict__ x, const float* __restrict__ avg,
                      const float* __restrict__ cyc64, const float* __restrict__ cycN,
                      float* __restrict__ Xe, float* __restrict__ Xo) {
    int i = blockIdx.x, r = blockIdx.y, b = blockIdx.z;
    int n = region_n(avg, r, b);
    int nn = n * n;
    int ri = r >> 2, rj = r & 3;
    int t = threadIdx.x;

    __shared__ __align__(16) float R[64 * 64];      // reused as partial buffer P
    __shared__ __align__(16) float M1[16 * 68];
    __shared__ float H[256];
    __shared__ float T1[256];
    __shared__ float T2[256];
    __shared__ float cyc64L[64];
    __shared__ float cnL[16];

    if (t < 64) cyc64L[t] = cyc64[t];
    if (t < n)  cnL[t] = cycN[(n * (n - 1)) / 2 + t];

    const float* base = x + (((size_t)(b * CIN + i)) * SS + ri * REG) * SS + rj * REG;
    float4* R4 = (float4*)R;
    {
        int u0 = t >> 4, c4 = t & 15;
        for (int it = 0; it < 4; ++it) {
            int u = it * 16 + u0;
            R4[u * 16 + c4] = *(const float4*)(base + (size_t)u * SS + c4 * 4);
        }
    }
    __syncthreads();

    // stage 1: M1[p][v] = sum_u cas64(p*u) * R[u][v], p < n.
    {
        int uq = t >> 6, ps = (t >> 4) & 3, vg = t & 15;
        int p0 = ps, p1 = ps + 4, p2 = ps + 8, p3 = ps + 12;
        int i0 = (p0 * (uq << 4)) & 63;
        int i1 = (p1 * (uq << 4)) & 63;
        int i2 = (p2 * (uq << 4)) & 63;
        int i3 = (p3 * (uq << 4)) & 63;
        float4 a0 = {0.f,0.f,0.f,0.f}, a1 = a0, a2 = a0, a3 = a0;
        int ubase = (uq << 4) * 16 + vg;
        for (int uu = 0; uu < 16; ++uu) {
            float4 rv = R4[ubase + uu * 16];
            if (p0 < n) { float c = cyc64L[i0];
                a0.x += c*rv.x; a0.y += c*rv.y; a0.z += c*rv.z; a0.w += c*rv.w; }
            if (p1 < n) { float c = cyc64L[i1];
                a1.x += c*rv.x; a1.y += c*rv.y; a1.z += c*rv.z; a1.w += c*rv.w; }
            if (p2 < n) { float c = cyc64L[i2];
                a2.x += c*rv.x; a2.y += c*rv.y; a2.z += c*rv.z; a2.w += c*rv.w; }
            if (p3 < n) { float c = cyc64L[i3];
                a3.x += c*rv.x; a3.y += c*rv.y; a3.z += c*rv.z; a3.w += c*rv.w; }
            i0 = (i0 + p0) & 63; i1 = (i1 + p1) & 63;
            i2 = (i2 + p2) & 63; i3 = (i3 + p3) & 63;
        }
        __syncthreads();            // all R reads complete before reuse as P
        float4* P4 = R4;            // P[uq][p][vg]
        int pb = (uq << 8) + vg;
        if (p0 < n) P4[pb + p0 * 16] = a0;
        if (p1 < n) P4[pb + p1 * 16] = a1;
        if (p2 < n) P4[pb + p2 * 16] = a2;
        if (p3 < n) P4[pb + p3 * 16] = a3;
        __syncthreads();
        int pr = t >> 4, vr = t & 15;
        if (pr < n) {
            float4 q0 = P4[pr * 16 + vr];
            float4 q1 = P4[256 + pr * 16 + vr];
            float4 q2 = P4[512 + pr * 16 + vr];
            float4 q3 = P4[768 + pr * 16 + vr];
            float4 s;
            s.x = (q0.x + q1.x) + (q2.x + q3.x);
            s.y = (q0.y + q1.y) + (q2.y + q3.y);
            s.z = (q0.z + q1.z) + (q2.z + q3.z);
            s.w = (q0.w + q1.w) + (q2.w + q3.w);
            *(float4*)&M1[pr * 68 + vr * 4] = s;
        }
    }
    __syncthreads();

    int p = 0, q = 0;
    if (t < nn) { p = t / n; q = t - p * n; }

    // stage 2: H[p][q] = sum_v M1[p][v] * cas64(q*v)
    if (t < nn) {
        float acc = 0.f;
        int idx = 0;
        for (int v = 0; v < 64; ++v) {
            acc += M1[p * 68 + v] * cyc64L[idx];
            idx = (idx + q) & 63;
        }
        H[t] = acc;
    }
    __syncthreads();

    // stage 3: true 2-D DHT of H (n x n) = row-column + correction
    if (t < nn) {
        float acc = 0.f;
        int idx = 0;
        for (int v = 0; v < n; ++v) {
            acc += H[p * n + v] * cnL[idx];
            idx += q; if (idx >= n) idx -= n;
        }
        T1[p * n + q] = acc;
    }
    __syncthreads();
    if (t < nn) {
        float acc = 0.f;
        int idx = 0;
        for (int u = 0; u < n; ++u) {
            acc += T1[u * n + q] * cnL[idx];
            idx += p; if (idx >= n) idx -= n;
        }
        T2[t] = acc;
    }
    __syncthreads();
    if (t < nn) {
        int pf = (p == 0) ? 0 : n - p;
        int qf = (q == 0) ? 0 : n - q;
        H[t] = 0.5f * (T2[p * n + q] + T2[pf * n + q] + T2[p * n + qf] - T2[pf * n + qf]);
    }
    __syncthreads();

    {
        size_t o = (((size_t)(b * 16 + r)) * CIN + i) * 256 + t;
        if (t < nn) {
            int fk = (t == 0) ? 0 : nn - t;
            float a = H[t], c = H[fk];
            Xe[o] = 0.5f * (a + c);
            Xo[o] = 0.5f * (a - c);
        } else {
            Xe[o] = 0.f;
            Xo[o] = 0.f;
        }
    }
}

// Fused channel-mix + inverse, ONE output per block: grid (o=32, br=128).
// z-phase is float4: thread (ig = t>>6) covers i in [ig*8, ig*8+8) and one
// float4 k-slot s = t&63 (k = 4s..4s+3). 32 vector loads/thread (was 128
// scalar) — same bytes, 4x fewer latency slots. Pad lanes are inert (Y pad
// and Xe/Xo tail are zeroed).
__global__ void k_zout(const float* __restrict__ Xe, const float* __restrict__ Xo,
                       const float* __restrict__ Y, const float* __restrict__ Yf,
                       const float* __restrict__ avg, const float* __restrict__ cyc64,
                       const float* __restrict__ cycN, float* __restrict__ out) {
    int o  = blockIdx.x;
    int br = blockIdx.y;
    int b = br >> 4, r = br & 15;
    int n = region_n(avg, r, b);
    int nn = n * n;
    int nnp4 = (nn + 3) >> 2;
    int t = threadIdx.x;

    __shared__ __align__(16) float zpart[4][256];
    __shared__ float Zs[256];
    __shared__ float T1[256];
    __shared__ float T2[256];
    __shared__ float Bk[256];
    __shared__ __align__(16) float E1[16 * 64];
    __shared__ __align__(16) float CTo[16 * 16 * 4];   // [p][u0] -> cas(p*(u0+16k))
    __shared__ float cyc64L[64];
    __shared__ float cnL[16];

    if (t < 64) cyc64L[t] = cyc64[t];
    if (t < n)  cnL[t] = cycN[(n * (n - 1)) / 2 + t];

    // ---- z-phase (partial over i), float4 loads
    int ig = t >> 6, s = t & 63;
    if (s < nnp4) {
        const float4* Yb4  = (const float4*)(Y  + (size_t)1024 * CPS16[n]);
        const float4* Yfb4 = (const float4*)(Yf + (size_t)1024 * CPS16[n]);
        const float4* Xe4 = (const float4*)(Xe + (size_t)br * CIN * 256);
        const float4* Xo4 = (const float4*)(Xo + (size_t)br * CIN * 256);
        float4 a = {0.f, 0.f, 0.f, 0.f};
#pragma unroll 4
        for (int ii = 0; ii < 8; ++ii) {
            int i = ig * 8 + ii;
            float4 xe = Xe4[i * 64 + s];
            float4 xo = Xo4[i * 64 + s];
            int yo = (i * COUT + o) * nnp4 + s;
            float4 y  = Yb4[yo];
            float4 yf = Yfb4[yo];
            a.x += xe.x * y.x + xo.x * yf.x;
            a.y += xe.y * y.y + xo.y * yf.y;
            a.z += xe.z * y.z + xo.z * yf.z;
            a.w += xe.w * y.w + xo.w * yf.w;
        }
        *(float4*)&zpart[ig][4 * s] = a;
    }
    __syncthreads();   // zpart + cyc64L/cnL visible

    // coefficient table for the final expansion (overlaps with reduce)
    {
        int pp = t >> 4, u0 = t & 15;
        float4 c;
        c.x = cyc64L[(pp * u0) & 63];
        c.y = cyc64L[(pp * (u0 + 16)) & 63];
        c.z = cyc64L[(pp * (u0 + 32)) & 63];
        c.w = cyc64L[(pp * (u0 + 48)) & 63];
        *(float4*)&CTo[t * 4] = c;
    }
    if (t < nn)
        Zs[t] = (zpart[0][t] + zpart[1][t]) + (zpart[2][t] + zpart[3][t]);

    int p = 0, q = 0;
    if (t < nn) { p = t / n; q = t - p * n; }
    __syncthreads();

    // inverse dht2 (row-column + correction), / nn
    if (t < nn) {
        float acc = 0.f;
        int idx = 0;
        for (int v = 0; v < n; ++v) {
            acc += Zs[p * n + v] * cnL[idx];
            idx += q; if (idx >= n) idx -= n;
        }
        T1[p * n + q] = acc;
    }
    __syncthreads();
    if (t < nn) {
        float acc = 0.f;
        int idx = 0;
        for (int u = 0; u < n; ++u) {
            acc += T1[u * n + q] * cnL[idx];
            idx += p; if (idx >= n) idx -= n;
        }
        T2[t] = acc;
    }
    __syncthreads();
    if (t < nn) {
        int pf = (p == 0) ? 0 : n - p;
        int qf = (q == 0) ? 0 : n - q;
        Bk[t] = 0.5f * (T2[p * n + q] + T2[pf * n + q] + T2[p * n + qf] - T2[pf * n + qf])
                / (float)nn;
    }
    __syncthreads();

    // E1[p][v] = sum_q Bk[p*n+q] * cas64(q*v)
    for (int mm = t; mm < n * 64; mm += 256) {
        int pp = mm >> 6, v = mm & 63;
        float acc = 0.f;
        int idx = 0;
        for (int qq = 0; qq < n; ++qq) {
            acc += Bk[pp * n + qq] * cyc64L[idx];
            idx = (idx + v) & 63;
        }
        E1[pp * 64 + v] = acc;
    }
    __syncthreads();

    // out[u][v] = (1/4096) sum_p E1[p][v] * cas64(p*u); p-outer, 4 u-rows/thread.
    int ri = r >> 2, rj = r & 3;
    float* ob = out + (((size_t)(b * COUT + o)) * SS + ri * REG) * SS + rj * REG;
    const float4* E14 = (const float4*)E1;
    const float4* CT4 = (const float4*)CTo;
    const float inv = 1.0f / 4096.0f;
    int u0 = t >> 4, vg = t & 15;
    float4 aA = {0.f,0.f,0.f,0.f}, aB = aA, aC = aA, aD = aA;
    for (int pp = 0; pp < n; ++pp) {
        float4 e = E14[pp * 16 + vg];
        float4 c = CT4[pp * 16 + u0];
        aA.x += c.x*e.x; aA.y += c.x*e.y; aA.z += c.x*e.z; aA.w += c.x*e.w;
        aB.x += c.y*e.x; aB.y += c.y*e.y; aB.z += c.y*e.z; aB.w += c.y*e.w;
        aC.x += c.z*e.x; aC.y += c.z*e.y; aC.z += c.z*e.z; aC.w += c.z*e.w;
        aD.x += c.w*e.x; aD.y += c.w*e.y; aD.z += c.w*e.z; aD.w += c.w*e.w;
    }
    aA.x *= inv; aA.y *= inv; aA.z *= inv; aA.w *= inv;
    aB.x *= inv; aB.y *= inv; aB.z *= inv; aB.w *= inv;
    aC.x *= inv; aC.y *= inv; aC.z *= inv; aC.w *= inv;
    aD.x *= inv; aD.y *= inv; aD.z *= inv; aD.w *= inv;
    *(float4*)(ob + (size_t)(u0)      * SS + vg * 4) = aA;
    *(float4*)(ob + (size_t)(16 + u0) * SS + vg * 4) = aB;
    *(float4*)(ob + (size_t)(32 + u0) * SS + vg * 4) = aC;
    *(float4*)(ob + (size_t)(48 + u0) * SS + vg * 4) = aD;
}

extern "C" void kernel_launch(void* const* d_in, const int* in_sizes, int n_in,
                              void* d_out, int out_size, void* d_ws, size_t ws_size,
                              hipStream_t stream) {
    const float* x   = (const float*)d_in[0];
    const float* err = (const float*)d_in[1];
    const float* wts = (const float*)d_in[2];
    float* out = (float*)d_out;
    char* ws = (char*)d_ws;

    float* avg   = (float*)(ws + AVG_OFF);
    float* cyc64 = (float*)(ws + C64_OFF);
    float* cycN  = (float*)(ws + CN_OFF);
    float* Y     = (float*)(ws + Y_OFF);
    float* Yf    = (float*)(ws + YF_OFF);
    float* Xe    = (float*)(ws + XE_OFF);
    float* Xo    = (float*)(ws + XO_OFF);

    k_prep<<<dim3(128 + 1 + CIN * COUT), 256, 0, stream>>>(err, wts, avg, cyc64, cycN, Y, Yf);
    k_fwd<<<dim3(CIN, 16, NB), 256, 0, stream>>>(x, avg, cyc64, cycN, Xe, Xo);
    k_zout<<<dim3(COUT, 128), 256, 0, stream>>>(Xe, Xo, Y, Yf, avg, cyc64, cycN, out);
}